// Round 8
// baseline (74.356 us; speedup 1.0000x reference)
//
#include <hip/hip_runtime.h>
#include <hip/hip_bf16.h>
#include <stdint.h>

// KAN layer: out[n,o] = sum_j w[o,j] * spline(x[n,j]; coeffs[o,j,:]) + bias[o]
// N=1024, D_IN=128, D_OUT=128, K=8, Catmull-Rom, uniform grid [-1,1].
// fp32 in/out (proven R1/R2/R4).
//
// R5/R6/R7 post-mortem: three structurally different LDS-staged MFMA kernels
// all land at dur 65-67us; TLP 2x (R7) had no effect. Either dur is harness-
// floored (40us ws poison fill + ~12us fixed, kernel already ~few us) or the
// shared skeleton (LDS stage -> barrier -> MFMA -> barrier -> LDS reduce)
// serializes. R8 removes the skeleton entirely:
//
// Key identity: for mfma_f32_16x16x32_bf16, A-frag lane (mo=lane&15,
// q=lane>>4) at K-step s holds A[mo][s*32+q*8+kk], kk=0..7. With our
// K = j*8+kslot packing, (s*32+q*8+kk)>>3 = s*4+q and kslot = kk -- so the
// lane's 8 A-slots are EXACTLY basis8(x[n0+mo][s*4+q]). Build A-frags in
// registers from one x scalar; build B-frags from w[o,j]*c[o,j,0:8] (32B
// contiguous per lane). Zero LDS, zero barriers, no K-split, no reduce.
// One wave = one 16x16 output tile, 32 MFMA steps over K=1024.
// Grid = 512 single-wave blocks (64 m-tiles x 8 o-tiles) = 2 waves/CU.
//
// C/D layout (m89-verified): col(o)=lane&15, row(m)=(lane>>4)*4+reg.

#define DIN 128
#define DOUT 128
#define KTOT 1024

typedef unsigned int u32;
typedef unsigned short u16;
typedef __attribute__((ext_vector_type(8))) short bf16x8;
typedef __attribute__((ext_vector_type(4))) float f32x4;

__device__ __forceinline__ u16 f2b(float f) {
    union { __hip_bfloat16 h; u16 u; } c;
    c.h = __float2bfloat16(f);   // RNE
    return c.u;
}

__global__ __launch_bounds__(64) void kan_wave(
    const float* __restrict__ x, const float* __restrict__ coeffs,
    const float* __restrict__ weights, const float* __restrict__ bias,
    float* __restrict__ out)
{
    const int lane = threadIdx.x;
    const int mo = lane & 15;          // A m-row, B o-row, D col
    const int q  = lane >> 4;          // k-quad

    const int mt = blockIdx.x & 63;    // 64 m-tiles
    const int ot = blockIdx.x >> 6;    // 8 o-tiles
    const int n0 = mt * 16;
    const int o0 = ot * 16;

    const float* xrow = x + (n0 + mo) * DIN;          // A source
    const float* crow = coeffs + (o0 + mo) * KTOT;    // B source
    const float* wrow = weights + (o0 + mo) * DIN;

    f32x4 acc = {0.0f, 0.0f, 0.0f, 0.0f};

    #pragma unroll 8
    for (int s = 0; s < 32; ++s) {
        const int j = s * 4 + q;

        // ---- A-frag: basis8(x[n0+mo][j]) in registers ----
        float xv = xrow[j];
        xv = fminf(fmaxf(xv, -1.0f), 1.0f);
        const float t = (xv + 1.0f) * 3.5f;           // h = 2/7
        int idx = (int)t; idx = idx > 6 ? 6 : idx;    // t>=0: trunc==floor
        const float u = t - (float)idx;
        const float u2 = u * u, u3 = u2 * u;
        const float b0 = 0.5f * (-u3 + 2.0f * u2 - u);
        const float b1 = 0.5f * (3.0f * u3 - 5.0f * u2 + 2.0f);
        const float b2 = 0.5f * (-3.0f * u3 + 4.0f * u2 + u);
        const float b3 = 0.5f * (u3 - u2);
        float r[8];
        #pragma unroll
        for (int k = 0; k < 8; ++k) r[k] = 0.0f;
        const int i0 = idx > 0 ? idx - 1 : 0;         // accumulate = clip fix
        const int i3 = idx < 6 ? idx + 2 : 7;
        r[i0] += b0; r[idx] += b1; r[idx + 1] += b2; r[i3] += b3;
        bf16x8 af;
        #pragma unroll
        for (int k = 0; k < 8; ++k) af[k] = (short)f2b(r[k]);

        // ---- B-frag: w[o,j] * c[o,j,0:8], 32B contiguous ----
        const float4 c0 = *(const float4*)(crow + j * 8);
        const float4 c1 = *(const float4*)(crow + j * 8 + 4);
        const float wv = wrow[j];
        bf16x8 bfr;
        bfr[0] = (short)f2b(c0.x * wv); bfr[1] = (short)f2b(c0.y * wv);
        bfr[2] = (short)f2b(c0.z * wv); bfr[3] = (short)f2b(c0.w * wv);
        bfr[4] = (short)f2b(c1.x * wv); bfr[5] = (short)f2b(c1.y * wv);
        bfr[6] = (short)f2b(c1.z * wv); bfr[7] = (short)f2b(c1.w * wv);

        acc = __builtin_amdgcn_mfma_f32_16x16x32_bf16(af, bfr, acc, 0, 0, 0);
    }

    // ---- epilogue: D[row=q*4+r][col=mo] + bias, direct store ----
    const float bv = bias[o0 + mo];
    #pragma unroll
    for (int r = 0; r < 4; ++r)
        out[(n0 + q * 4 + r) * DOUT + o0 + mo] = acc[r] + bv;
}

extern "C" void kernel_launch(void* const* d_in, const int* in_sizes, int n_in,
                              void* d_out, int out_size, void* d_ws, size_t ws_size,
                              hipStream_t stream) {
    const float* x       = (const float*)d_in[0];
    const float* coeffs  = (const float*)d_in[1];
    const float* weights = (const float*)d_in[2];
    const float* bias    = (const float*)d_in[3];
    float* out = (float*)d_out;
    const int N = in_sizes[0] / DIN;              // 1024
    kan_wave<<<(N / 16) * (DOUT / 16), 64, 0, stream>>>(
        x, coeffs, weights, bias, out);
}

// Round 9
// 65.283 us; speedup vs baseline: 1.1390x; 1.1390x over previous
//
#include <hip/hip_runtime.h>
#include <hip/hip_bf16.h>
#include <stdint.h>

// KAN layer: out[n,o] = sum_j w[o,j] * spline(x[n,j]; coeffs[o,j,:]) + bias[o]
// N=1024, D_IN=128, D_OUT=128, K=8, Catmull-Rom, uniform grid [-1,1].
// fp32 in/out (proven R1/R2/R4).
//
// R8 post-mortem: skeleton-free 1-wave kernel regressed (+9us) -> dur_us DOES
// resolve kernel deltas; R5-R7 plateau (~13us kernel) is real. Shared trait:
// per-MFMA-step VALU chains (w*c mul + 16 cvt_bf16) and scattered loads
// feeding each step, recomputing W' conversion 64x chip-wide.
//
// R9: prep + pure GEMM split.
//  K1 (grid 576x256): writes to ws (poisoned each call, fully rewritten):
//     ws0 = basis bf16 [1024 n][1024 k]  (k = j*8+slot, dense Catmull-Rom,
//           accumulate handles boundary clip)   -- 2 MB
//     ws1 = W' bf16 [128 o][1024 k] = w[o,j]*c[o,j,slot]  -- 256 KB
//     all loads/stores coalesced 16B/lane; conversions done ONCE.
//  K2 (grid 64x8, 256 thr = 4 waves): pure bf16 GEMM C = ws0 . ws1^T.
//     wave = K-quarter (256 k = 8 MFMA steps); per step just two b128
//     global loads + mfma_16x16x32_bf16 -- no VALU in the chain; 16
//     independent loads fully hoistable. LDS only for the 4-way K reduce.
//     2 blocks/CU, 2 waves/SIMD.
// Same-stream kernel ordering guarantees ws visibility K1 -> K2.
//
// MFMA 16x16x32 bf16 (R5..R7-verified): A/B-frag lane (mo=lane&15,q=lane>>4)
// holds [mo][k=32s+8q+kk]; C/D: col=lane&15, row=(lane>>4)*4+reg.

#define DIN 128
#define DOUT 128
#define KTOT 1024

typedef unsigned int u32;
typedef unsigned short u16;
typedef __attribute__((ext_vector_type(8))) short bf16x8;
typedef __attribute__((ext_vector_type(4))) float f32x4;

union H8 { u16 s[8]; uint4 v; };

__device__ __forceinline__ u16 f2b(float f) {
    union { __hip_bfloat16 h; u16 u; } c;
    c.h = __float2bfloat16(f);   // RNE
    return c.u;
}

// ---- K1: build basis (blocks 0..511) and W' (blocks 512..575) ----
__global__ __launch_bounds__(256) void kan_prep(
    const float* __restrict__ x, const float* __restrict__ coeffs,
    const float* __restrict__ weights, u16* __restrict__ ws0,
    u16* __restrict__ ws1)
{
    const int tid = threadIdx.x;
    if (blockIdx.x < 512) {
        const int task = blockIdx.x * 256 + tid;   // [0, 131072) = n*128+j
        float xv = x[task];                        // coalesced
        xv = fminf(fmaxf(xv, -1.0f), 1.0f);
        const float t = (xv + 1.0f) * 3.5f;        // h = 2/7
        int idx = (int)t; idx = idx > 6 ? 6 : idx; // t>=0: trunc==floor
        const float u = t - (float)idx;
        const float u2 = u * u, u3 = u2 * u;
        const float b0 = 0.5f * (-u3 + 2.0f * u2 - u);
        const float b1 = 0.5f * (3.0f * u3 - 5.0f * u2 + 2.0f);
        const float b2 = 0.5f * (-3.0f * u3 + 4.0f * u2 + u);
        const float b3 = 0.5f * (u3 - u2);
        float r[8];
        #pragma unroll
        for (int k = 0; k < 8; ++k) r[k] = 0.0f;
        const int i0 = idx > 0 ? idx - 1 : 0;      // accumulate = clip fix
        const int i3 = idx < 6 ? idx + 2 : 7;
        r[i0] += b0; r[idx] += b1; r[idx + 1] += b2; r[i3] += b3;
        H8 h;
        #pragma unroll
        for (int k = 0; k < 8; ++k) h.s[k] = f2b(r[k]);
        *(uint4*)(ws0 + task * 8) = h.v;           // coalesced 16B/lane
    } else {
        const int task = (blockIdx.x - 512) * 256 + tid;  // [0,16384)=o*128+j
        const float wv = weights[task];            // coalesced
        const float4 c0 = *(const float4*)(coeffs + task * 8);
        const float4 c1 = *(const float4*)(coeffs + task * 8 + 4);
        H8 h;
        h.s[0] = f2b(c0.x * wv); h.s[1] = f2b(c0.y * wv);
        h.s[2] = f2b(c0.z * wv); h.s[3] = f2b(c0.w * wv);
        h.s[4] = f2b(c1.x * wv); h.s[5] = f2b(c1.y * wv);
        h.s[6] = f2b(c1.z * wv); h.s[7] = f2b(c1.w * wv);
        *(uint4*)(ws1 + task * 8) = h.v;           // coalesced 16B/lane
    }
}

// ---- K2: pure GEMM out = basis . W'^T + bias ----
__global__ __launch_bounds__(256) void kan_gemm(
    const u16* __restrict__ ws0, const u16* __restrict__ ws1,
    const float* __restrict__ bias, float* __restrict__ out)
{
    __shared__ float sC[4 * 256];

    const int tid  = threadIdx.x;
    const int wave = tid >> 6;                 // K-quarter
    const int lane = tid & 63;
    const int mo = lane & 15;
    const int q  = lane >> 4;
    const int n0 = blockIdx.x * 16;
    const int o0 = blockIdx.y * 16;

    const u16* ap = ws0 + (n0 + mo) * KTOT + wave * 256 + q * 8;
    const u16* bp = ws1 + (o0 + mo) * KTOT + wave * 256 + q * 8;

    f32x4 acc = {0.0f, 0.0f, 0.0f, 0.0f};
    #pragma unroll
    for (int s = 0; s < 8; ++s) {
        bf16x8 af = *(const bf16x8*)(ap + s * 32);
        bf16x8 bf = *(const bf16x8*)(bp + s * 32);
        acc = __builtin_amdgcn_mfma_f32_16x16x32_bf16(af, bf, acc, 0, 0, 0);
    }

    #pragma unroll
    for (int r = 0; r < 4; ++r)
        sC[wave * 256 + (q * 4 + r) * 16 + mo] = acc[r];
    __syncthreads();

    const int row = tid >> 4, col = tid & 15;
    float v = sC[tid] + sC[256 + tid] + sC[512 + tid] + sC[768 + tid];
    out[(n0 + row) * DOUT + o0 + col] = v + bias[o0 + col];
}

extern "C" void kernel_launch(void* const* d_in, const int* in_sizes, int n_in,
                              void* d_out, int out_size, void* d_ws, size_t ws_size,
                              hipStream_t stream) {
    const float* x       = (const float*)d_in[0];
    const float* coeffs  = (const float*)d_in[1];
    const float* weights = (const float*)d_in[2];
    const float* bias    = (const float*)d_in[3];
    float* out = (float*)d_out;
    u16* ws0 = (u16*)d_ws;                          // 2 MB basis
    u16* ws1 = ws0 + 1024 * KTOT;                   // 256 KB W'
    kan_prep<<<576, 256, 0, stream>>>(x, coeffs, weights, ws0, ws1);
    dim3 grid(1024 / 16, DOUT / 16);                // 64 x 8
    kan_gemm<<<grid, 256, 0, stream>>>(ws0, ws1, bias, out);
}

// Round 10
// 63.335 us; speedup vs baseline: 1.1740x; 1.0308x over previous
//
#include <hip/hip_runtime.h>
#include <hip/hip_bf16.h>
#include <stdint.h>

// KAN layer: out[n,o] = sum_j w[o,j] * spline(x[n,j]; coeffs[o,j,:]) + bias[o]
// N=1024, D_IN=128, D_OUT=128, K=8, Catmull-Rom, uniform grid [-1,1].
// fp32 in/out (proven R1/R2/R4).
//
// Plateau: R5(65.3)/R6(65.1)/R7(66.9)/R9(65.3) -- four orthogonal structures
// identical; R4(+28)/R8(+9) prove dur resolves kernel deltas. Shared residual
// candidate: all had >=16-cache-line-per-instruction global loads (2-4KB lane
// stride) in the MFMA phase. R10 removes the last global access from the MFMA
// loop entirely:
//  - 512 blocks (64 m x 8 o tiles), 256 thr = 4 waves, 2 blocks/CU
//  - phase 1: stage basis tile (16n x 1024k bf16, 32KB) AND W' tile
//    (16o x 1024k bf16, 32KB) into LDS from PERFECTLY coalesced global reads
//    (basis: 2048 consecutive floats; W': 32B/lane consecutive chunks)
//  - XOR swizzle (16B-unit idx ^ (row&7)) -> conflict-free, no padding,
//    tiles exactly 64KB total (static LDS limit); reduce buffer ALIASES the
//    basis tile (all basis reads complete before reduce writes)
//  - phase 2: pure LDS GEMM, 4-way K-split: 16 ds_read_b128 + 8 MFMA/wave
//  - phase 3: 4-way partial reduce + bias + coalesced store. One launch.
//
// MFMA 16x16x32 bf16 (R5..R9-verified): A/B-frag lane (mo=lane&15,q=lane>>4)
// holds [mo][k=32S+8q+kk]; C/D: col=lane&15, row=(lane>>4)*4+reg.

#define DIN 128
#define DOUT 128
#define KTOT 1024

typedef unsigned int u32;
typedef unsigned short u16;
typedef __attribute__((ext_vector_type(8))) short bf16x8;
typedef __attribute__((ext_vector_type(4))) float f32x4;

union H8 { u16 s[8]; uint4 v; };

__device__ __forceinline__ u16 f2b(float f) {
    union { __hip_bfloat16 h; u16 u; } c;
    c.h = __float2bfloat16(f);   // RNE
    return c.u;
}

__global__ __launch_bounds__(256) void kan_fused(
    const float* __restrict__ x, const float* __restrict__ coeffs,
    const float* __restrict__ weights, const float* __restrict__ bias,
    float* __restrict__ out)
{
    // 16 rows x 1024 halfwords each; 16B-unit index u is XOR-swizzled by
    // (row&7) -> bank-conflict-free reads without padding.
    __shared__ __align__(16) u16 sBas[16 * KTOT];   // 32 KB (aliased by sC)
    __shared__ __align__(16) u16 sWp [16 * KTOT];   // 32 KB
    float* sC = (float*)sBas;                       // 4 KB partials (aliased)

    const int tid  = threadIdx.x;
    const int wave = tid >> 6;
    const int lane = tid & 63;
    const int n0 = blockIdx.x * 16;                 // 64 m-tiles
    const int o0 = blockIdx.y * 16;                 // 8 o-tiles

    // ---- Phase 1a: basis tile. 2048 tasks (row,j), coalesced x reads ----
    #pragma unroll
    for (int it = 0; it < 8; ++it) {
        const int task = tid + it * 256;            // row*128 + j
        const int row = task >> 7;
        const int j = task & 127;
        float xv = x[n0 * DIN + task];              // consecutive floats
        xv = fminf(fmaxf(xv, -1.0f), 1.0f);
        const float t = (xv + 1.0f) * 3.5f;         // h = 2/7
        int idx = (int)t; idx = idx > 6 ? 6 : idx;  // t>=0: trunc==floor
        const float u = t - (float)idx;
        const float u2 = u * u, u3 = u2 * u;
        const float b0 = 0.5f * (-u3 + 2.0f * u2 - u);
        const float b1 = 0.5f * (3.0f * u3 - 5.0f * u2 + 2.0f);
        const float b2 = 0.5f * (-3.0f * u3 + 4.0f * u2 + u);
        const float b3 = 0.5f * (u3 - u2);
        float r[8];
        #pragma unroll
        for (int k = 0; k < 8; ++k) r[k] = 0.0f;
        const int i0 = idx > 0 ? idx - 1 : 0;       // accumulate = clip fix
        const int i3 = idx < 6 ? idx + 2 : 7;
        r[i0] += b0; r[idx] += b1; r[idx + 1] += b2; r[i3] += b3;
        H8 h;
        #pragma unroll
        for (int k = 0; k < 8; ++k) h.s[k] = f2b(r[k]);
        const int uu = j ^ (row & 7);               // swizzled 16B unit
        *(uint4*)(sBas + row * KTOT + uu * 8) = h.v;
    }

    // ---- Phase 1b: W' tile. 2048 tasks (o,j), coalesced 32B/lane ----
    #pragma unroll
    for (int it = 0; it < 8; ++it) {
        const int task = tid + it * 256;            // o*128 + j
        const int o = task >> 7;
        const int j = task & 127;
        const float wv = weights[o0 * DIN + task];  // consecutive floats
        const float4 c0 = *(const float4*)(coeffs + o0 * KTOT + task * 8);
        const float4 c1 = *(const float4*)(coeffs + o0 * KTOT + task * 8 + 4);
        H8 h;
        h.s[0] = f2b(c0.x * wv); h.s[1] = f2b(c0.y * wv);
        h.s[2] = f2b(c0.z * wv); h.s[3] = f2b(c0.w * wv);
        h.s[4] = f2b(c1.x * wv); h.s[5] = f2b(c1.y * wv);
        h.s[6] = f2b(c1.z * wv); h.s[7] = f2b(c1.w * wv);
        const int uu = j ^ (o & 7);
        *(uint4*)(sWp + o * KTOT + uu * 8) = h.v;
    }
    __syncthreads();

    // ---- Phase 2: pure LDS MFMA, wave = K-quarter (8 steps) ----
    const int mo = lane & 15;
    const int q  = lane >> 4;
    const int sw = mo & 7;                          // read-side swizzle
    f32x4 acc = {0.0f, 0.0f, 0.0f, 0.0f};
    #pragma unroll
    for (int s = 0; s < 8; ++s) {
        const int S = wave * 8 + s;                 // global K-step
        const int uu = (S * 4 + q) ^ sw;            // 16B unit
        bf16x8 af = *(const bf16x8*)(sBas + mo * KTOT + uu * 8);
        bf16x8 bf = *(const bf16x8*)(sWp  + mo * KTOT + uu * 8);
        acc = __builtin_amdgcn_mfma_f32_16x16x32_bf16(af, bf, acc, 0, 0, 0);
    }
    __syncthreads();                                // basis reads done

    // ---- Phase 3: 4-way reduce (sC aliases sBas) + bias + store ----
    #pragma unroll
    for (int r = 0; r < 4; ++r)
        sC[wave * 256 + (q * 4 + r) * 16 + mo] = acc[r];
    __syncthreads();

    const int row = tid >> 4, col = tid & 15;
    float v = sC[tid] + sC[256 + tid] + sC[512 + tid] + sC[768 + tid];
    out[(n0 + row) * DOUT + o0 + col] = v + bias[o0 + col];
}

extern "C" void kernel_launch(void* const* d_in, const int* in_sizes, int n_in,
                              void* d_out, int out_size, void* d_ws, size_t ws_size,
                              hipStream_t stream) {
    const float* x       = (const float*)d_in[0];
    const float* coeffs  = (const float*)d_in[1];
    const float* weights = (const float*)d_in[2];
    const float* bias    = (const float*)d_in[3];
    float* out = (float*)d_out;
    const int N = in_sizes[0] / DIN;                // 1024
    dim3 grid(N / 16, DOUT / 16);                   // 64 x 8 = 512 blocks
    kan_fused<<<grid, 256, 0, stream>>>(x, coeffs, weights, bias, out);
}

// Round 11
// 62.382 us; speedup vs baseline: 1.1919x; 1.0153x over previous
//
#include <hip/hip_runtime.h>
#include <hip/hip_bf16.h>
#include <stdint.h>

// KAN layer: out[n,o] = sum_j w[o,j] * spline(x[n,j]; coeffs[o,j,:]) + bias[o]
// N=1024, D_IN=128, D_OUT=128, K=8, Catmull-Rom, uniform grid [-1,1].
// fp32 in/out (proven R1/R2/R4).
//
// R10 post-mortem: pure-LDS MFMA phase -> 63.33 (-1.8us, first real win since
// R5). Budget: 40us ws-poison fill + ~12us graph ops + kernel ~10us, of which
// work is ~1-2us -> the rest is exposed staging-chain latency at 8 waves/CU.
//
// R11 = R10 structure with 2x TLP and half the staging chain:
//  - 512-thread blocks (8 waves): staging 8 iters/thread (was 16)
//  - phase 2: 8-way K-split, 4 MFMA steps/wave
//  - LDS unchanged 64KB (basis 32KB + W' 32KB) -> 2 blocks/CU, 16 waves/CU
//  - 8-way partial reduce (threads 0..255), sC aliases basis tile
//  - XOR swizzle (16B-unit ^ (row&7)): phase-2 reads are 2-way bank
//    aliased = free (m136); writes conflict-free
//
// MFMA 16x16x32 bf16 (R5..R10-verified): A/B-frag lane (mo=lane&15,
// q=lane>>4) holds [mo][k=32S+8q+kk]; C/D: col=lane&15, row=(lane>>4)*4+reg.

#define DIN 128
#define DOUT 128
#define KTOT 1024

typedef unsigned int u32;
typedef unsigned short u16;
typedef __attribute__((ext_vector_type(8))) short bf16x8;
typedef __attribute__((ext_vector_type(4))) float f32x4;

union H8 { u16 s[8]; uint4 v; };

__device__ __forceinline__ u16 f2b(float f) {
    union { __hip_bfloat16 h; u16 u; } c;
    c.h = __float2bfloat16(f);   // RNE
    return c.u;
}

__global__ __launch_bounds__(512) void kan_fused(
    const float* __restrict__ x, const float* __restrict__ coeffs,
    const float* __restrict__ weights, const float* __restrict__ bias,
    float* __restrict__ out)
{
    __shared__ __align__(16) u16 sBas[16 * KTOT];   // 32 KB (aliased by sC)
    __shared__ __align__(16) u16 sWp [16 * KTOT];   // 32 KB
    float* sC = (float*)sBas;                       // 8 KB partials (aliased)

    const int tid  = threadIdx.x;
    const int wave = tid >> 6;
    const int lane = tid & 63;
    const int n0 = blockIdx.x * 16;                 // 64 m-tiles
    const int o0 = blockIdx.y * 16;                 // 8 o-tiles

    // ---- Phase 1a: basis tile. 2048 tasks (row,j), coalesced x reads ----
    #pragma unroll
    for (int it = 0; it < 4; ++it) {
        const int task = tid + it * 512;            // row*128 + j
        const int row = task >> 7;
        const int j = task & 127;
        float xv = x[n0 * DIN + task];              // consecutive floats
        xv = fminf(fmaxf(xv, -1.0f), 1.0f);
        const float t = (xv + 1.0f) * 3.5f;         // h = 2/7
        int idx = (int)t; idx = idx > 6 ? 6 : idx;  // t>=0: trunc==floor
        const float u = t - (float)idx;
        const float u2 = u * u, u3 = u2 * u;
        const float b0 = 0.5f * (-u3 + 2.0f * u2 - u);
        const float b1 = 0.5f * (3.0f * u3 - 5.0f * u2 + 2.0f);
        const float b2 = 0.5f * (-3.0f * u3 + 4.0f * u2 + u);
        const float b3 = 0.5f * (u3 - u2);
        float r[8];
        #pragma unroll
        for (int k = 0; k < 8; ++k) r[k] = 0.0f;
        const int i0 = idx > 0 ? idx - 1 : 0;       // accumulate = clip fix
        const int i3 = idx < 6 ? idx + 2 : 7;
        r[i0] += b0; r[idx] += b1; r[idx + 1] += b2; r[i3] += b3;
        H8 h;
        #pragma unroll
        for (int k = 0; k < 8; ++k) h.s[k] = f2b(r[k]);
        const int uu = j ^ (row & 7);               // swizzled 16B unit
        *(uint4*)(sBas + row * KTOT + uu * 8) = h.v;
    }

    // ---- Phase 1b: W' tile. 2048 tasks (o,j), coalesced 32B/lane ----
    #pragma unroll
    for (int it = 0; it < 4; ++it) {
        const int task = tid + it * 512;            // o*128 + j
        const int o = task >> 7;
        const int j = task & 127;
        const float wv = weights[o0 * DIN + task];  // consecutive floats
        const float4 c0 = *(const float4*)(coeffs + o0 * KTOT + task * 8);
        const float4 c1 = *(const float4*)(coeffs + o0 * KTOT + task * 8 + 4);
        H8 h;
        h.s[0] = f2b(c0.x * wv); h.s[1] = f2b(c0.y * wv);
        h.s[2] = f2b(c0.z * wv); h.s[3] = f2b(c0.w * wv);
        h.s[4] = f2b(c1.x * wv); h.s[5] = f2b(c1.y * wv);
        h.s[6] = f2b(c1.z * wv); h.s[7] = f2b(c1.w * wv);
        const int uu = j ^ (o & 7);
        *(uint4*)(sWp + o * KTOT + uu * 8) = h.v;
    }
    __syncthreads();

    // ---- Phase 2: pure LDS MFMA, wave = K-eighth (4 steps) ----
    const int mo = lane & 15;
    const int q  = lane >> 4;
    const int sw = mo & 7;                          // read-side swizzle
    f32x4 acc = {0.0f, 0.0f, 0.0f, 0.0f};
    #pragma unroll
    for (int s = 0; s < 4; ++s) {
        const int S = wave * 4 + s;                 // global K-step
        const int uu = (S * 4 + q) ^ sw;            // 16B unit
        bf16x8 af = *(const bf16x8*)(sBas + mo * KTOT + uu * 8);
        bf16x8 bf = *(const bf16x8*)(sWp  + mo * KTOT + uu * 8);
        acc = __builtin_amdgcn_mfma_f32_16x16x32_bf16(af, bf, acc, 0, 0, 0);
    }
    __syncthreads();                                // basis reads done

    // ---- Phase 3: 8-way reduce (sC aliases sBas) + bias + store ----
    #pragma unroll
    for (int r = 0; r < 4; ++r)
        sC[wave * 256 + (q * 4 + r) * 16 + mo] = acc[r];
    __syncthreads();

    if (tid < 256) {
        const int row = tid >> 4, col = tid & 15;
        float v = sC[tid];
        #pragma unroll
        for (int w = 1; w < 8; ++w) v += sC[w * 256 + tid];
        out[(n0 + row) * DOUT + o0 + col] = v + bias[o0 + col];
    }
}

extern "C" void kernel_launch(void* const* d_in, const int* in_sizes, int n_in,
                              void* d_out, int out_size, void* d_ws, size_t ws_size,
                              hipStream_t stream) {
    const float* x       = (const float*)d_in[0];
    const float* coeffs  = (const float*)d_in[1];
    const float* weights = (const float*)d_in[2];
    const float* bias    = (const float*)d_in[3];
    float* out = (float*)d_out;
    const int N = in_sizes[0] / DIN;                // 1024
    dim3 grid(N / 16, DOUT / 16);                   // 64 x 8 = 512 blocks
    kan_fused<<<grid, 512, 0, stream>>>(x, coeffs, weights, bias, out);
}

// Round 12
// 62.225 us; speedup vs baseline: 1.1950x; 1.0025x over previous
//
#include <hip/hip_runtime.h>
#include <hip/hip_bf16.h>
#include <stdint.h>

// KAN layer: out[n,o] = sum_j w[o,j] * spline(x[n,j]; coeffs[o,j,:]) + bias[o]
// N=1024, D_IN=128, D_OUT=128, K=8, Catmull-Rom, uniform grid [-1,1].
// fp32 in/out (proven R1/R2/R4).
//
// R10 (-1.8us) and R11 (-0.95us) both paid via: shorter per-thread staging
// chain + more waves/CU. R12 takes the same lever to the hardware limit:
//  - 1024-thread blocks (16 waves): staging 2 iters/thread (was 4)
//  - phase 2: 16-way K-split, 2 MFMA steps/wave
//  - LDS 64KB (basis 32KB + W' 32KB) -> 2 blocks/CU, 32 waves/CU (max)
//  - 16-way partial reduce (threads 0..255; sC 16KB aliases basis tile)
//  - XOR swizzle (16B-unit ^ (row&7)): phase-2 reads 2-way aliased = free
// Budget: dur = 40.3us ws-poison fill + ~12us graph ops + kernel (~10us at
// R11). Floor estimate ~54-56us total.
//
// MFMA 16x16x32 bf16 (R5..R11-verified): A/B-frag lane (mo=lane&15,
// q=lane>>4) holds [mo][k=32S+8q+kk]; C/D: col=lane&15, row=(lane>>4)*4+reg.

#define DIN 128
#define DOUT 128
#define KTOT 1024

typedef unsigned int u32;
typedef unsigned short u16;
typedef __attribute__((ext_vector_type(8))) short bf16x8;
typedef __attribute__((ext_vector_type(4))) float f32x4;

union H8 { u16 s[8]; uint4 v; };

__device__ __forceinline__ u16 f2b(float f) {
    union { __hip_bfloat16 h; u16 u; } c;
    c.h = __float2bfloat16(f);   // RNE
    return c.u;
}

__global__ __launch_bounds__(1024) void kan_fused(
    const float* __restrict__ x, const float* __restrict__ coeffs,
    const float* __restrict__ weights, const float* __restrict__ bias,
    float* __restrict__ out)
{
    __shared__ __align__(16) u16 sBas[16 * KTOT];   // 32 KB (aliased by sC)
    __shared__ __align__(16) u16 sWp [16 * KTOT];   // 32 KB
    float* sC = (float*)sBas;                       // 16 KB partials (alias)

    const int tid  = threadIdx.x;
    const int wave = tid >> 6;                      // 0..15
    const int lane = tid & 63;
    const int n0 = blockIdx.x * 16;                 // 64 m-tiles
    const int o0 = blockIdx.y * 16;                 // 8 o-tiles

    // ---- Phase 1a: basis tile. 2048 tasks (row,j), coalesced x reads ----
    #pragma unroll
    for (int it = 0; it < 2; ++it) {
        const int task = tid + it * 1024;           // row*128 + j
        const int row = task >> 7;
        const int j = task & 127;
        float xv = x[n0 * DIN + task];              // consecutive floats
        xv = fminf(fmaxf(xv, -1.0f), 1.0f);
        const float t = (xv + 1.0f) * 3.5f;         // h = 2/7
        int idx = (int)t; idx = idx > 6 ? 6 : idx;  // t>=0: trunc==floor
        const float u = t - (float)idx;
        const float u2 = u * u, u3 = u2 * u;
        const float b0 = 0.5f * (-u3 + 2.0f * u2 - u);
        const float b1 = 0.5f * (3.0f * u3 - 5.0f * u2 + 2.0f);
        const float b2 = 0.5f * (-3.0f * u3 + 4.0f * u2 + u);
        const float b3 = 0.5f * (u3 - u2);
        float r[8];
        #pragma unroll
        for (int k = 0; k < 8; ++k) r[k] = 0.0f;
        const int i0 = idx > 0 ? idx - 1 : 0;       // accumulate = clip fix
        const int i3 = idx < 6 ? idx + 2 : 7;
        r[i0] += b0; r[idx] += b1; r[idx + 1] += b2; r[i3] += b3;
        H8 h;
        #pragma unroll
        for (int k = 0; k < 8; ++k) h.s[k] = f2b(r[k]);
        const int uu = j ^ (row & 7);               // swizzled 16B unit
        *(uint4*)(sBas + row * KTOT + uu * 8) = h.v;
    }

    // ---- Phase 1b: W' tile. 2048 tasks (o,j), coalesced 32B/lane ----
    #pragma unroll
    for (int it = 0; it < 2; ++it) {
        const int task = tid + it * 1024;           // o*128 + j
        const int o = task >> 7;
        const int j = task & 127;
        const float wv = weights[o0 * DIN + task];  // consecutive floats
        const float4 c0 = *(const float4*)(coeffs + o0 * KTOT + task * 8);
        const float4 c1 = *(const float4*)(coeffs + o0 * KTOT + task * 8 + 4);
        H8 h;
        h.s[0] = f2b(c0.x * wv); h.s[1] = f2b(c0.y * wv);
        h.s[2] = f2b(c0.z * wv); h.s[3] = f2b(c0.w * wv);
        h.s[4] = f2b(c1.x * wv); h.s[5] = f2b(c1.y * wv);
        h.s[6] = f2b(c1.z * wv); h.s[7] = f2b(c1.w * wv);
        const int uu = j ^ (o & 7);
        *(uint4*)(sWp + o * KTOT + uu * 8) = h.v;
    }
    __syncthreads();

    // ---- Phase 2: pure LDS MFMA, wave = K-sixteenth (2 steps) ----
    const int mo = lane & 15;
    const int q  = lane >> 4;
    const int sw = mo & 7;                          // read-side swizzle
    f32x4 acc = {0.0f, 0.0f, 0.0f, 0.0f};
    #pragma unroll
    for (int s = 0; s < 2; ++s) {
        const int S = wave * 2 + s;                 // global K-step
        const int uu = (S * 4 + q) ^ sw;            // 16B unit
        bf16x8 af = *(const bf16x8*)(sBas + mo * KTOT + uu * 8);
        bf16x8 bf = *(const bf16x8*)(sWp  + mo * KTOT + uu * 8);
        acc = __builtin_amdgcn_mfma_f32_16x16x32_bf16(af, bf, acc, 0, 0, 0);
    }
    __syncthreads();                                // basis reads done

    // ---- Phase 3: 16-way reduce (sC aliases sBas) + bias + store ----
    #pragma unroll
    for (int r = 0; r < 4; ++r)
        sC[wave * 256 + (q * 4 + r) * 16 + mo] = acc[r];
    __syncthreads();

    if (tid < 256) {
        const int row = tid >> 4, col = tid & 15;
        float v = sC[tid];
        #pragma unroll
        for (int w = 1; w < 16; ++w) v += sC[w * 256 + tid];
        out[(n0 + row) * DOUT + o0 + col] = v + bias[o0 + col];
    }
}

extern "C" void kernel_launch(void* const* d_in, const int* in_sizes, int n_in,
                              void* d_out, int out_size, void* d_ws, size_t ws_size,
                              hipStream_t stream) {
    const float* x       = (const float*)d_in[0];
    const float* coeffs  = (const float*)d_in[1];
    const float* weights = (const float*)d_in[2];
    const float* bias    = (const float*)d_in[3];
    float* out = (float*)d_out;
    const int N = in_sizes[0] / DIN;                // 1024
    dim3 grid(N / 16, DOUT / 16);                   // 64 x 8 = 512 blocks
    kan_fused<<<grid, 1024, 0, stream>>>(x, coeffs, weights, bias, out);
}